// Round 7
// baseline (415.351 us; speedup 1.0000x reference)
//
#include <hip/hip_runtime.h>
#include <math.h>
#include <limits.h>

#define QN 1024
#define NN 50000
#define NPAD 50048        /* 391*128 exactly */
#define DD 512
#define KNN 10
#define NT 128
#define QTB 128
#define BK 32
#define NS 391
#define QB 8
#define NSAMP 31          /* sampled slices for threshold */
#define NREST (NS - NSAMP)    /* 360 */
#define NPAIR (NREST / 2)     /* 180 */
#define CAP 512

/* workspace layout, in 4-byte words */
#define WS_D2  0
#define WS_TAU 50048                       /* u64[1024] */
#define WS_CNT (WS_TAU + 2048)
#define WS_XH  (WS_CNT + 1024)
#define WS_XL  (WS_XH + QN * DD / 2)
#define WS_CKS (WS_XL + QN * DD / 2)       /* u64[QN*NSAMP*KNN] */
#define WS_BUF (WS_CKS + QN * NSAMP * KNN * 2)
#define WS_DH  (WS_BUF + QN * CAP * 2)     /* tiled data hi: 391*16*8192 B */
#define WS_DL  (WS_DH + NS * 16 * 2048)
#define WS_END (WS_DL + NS * 16 * 2048)

typedef __attribute__((ext_vector_type(8))) short short8;
typedef __attribute__((ext_vector_type(4))) float f32x4;
typedef unsigned long long u64;

__device__ __forceinline__ u64 mkkey(float f, int idx) {
  unsigned u = __float_as_uint(f);
  unsigned m = u ^ ((unsigned)((int)u >> 31) | 0x80000000u);
  return ((u64)m << 32) | (unsigned)idx;
}

__device__ __forceinline__ void cvt2(float x, float y, unsigned& hi, unsigned& lo) {
  unsigned ux = __float_as_uint(x), uy = __float_as_uint(y);
  unsigned rx = ux + 0x7fffu + ((ux >> 16) & 1u);
  unsigned ry = uy + 0x7fffu + ((uy >> 16) & 1u);
  hi = (rx >> 16) | (ry & 0xffff0000u);
  float xl = x - __uint_as_float(rx & 0xffff0000u);
  float yl = y - __uint_as_float(ry & 0xffff0000u);
  unsigned uxl = __float_as_uint(xl), uyl = __float_as_uint(yl);
  unsigned rxl = uxl + 0x7fffu + ((uxl >> 16) & 1u);
  unsigned ryl = uyl + 0x7fffu + ((uyl >> 16) & 1u);
  lo = (rxl >> 16) | (ryl & 0xffff0000u);
}

__device__ __forceinline__ void glds16(const void* g, void* l) {
  __builtin_amdgcn_global_load_lds(
      (const __attribute__((address_space(1))) unsigned*)g,
      (__attribute__((address_space(3))) unsigned*)l, 16, 0, 0);
}

__device__ __forceinline__ void ins10(u64* kl, u64 k) {
#pragma unroll
  for (int u = 0; u < KNN; u++) {
    u64 lo = (k < kl[u]) ? k : kl[u];
    u64 hi = (k < kl[u]) ? kl[u] : k;
    kl[u] = lo; k = hi;
  }
}

/* ---------------- K0: preconvert X to split-bf16 row-major -------------- */
__global__ __launch_bounds__(256) void convx_kernel(
    const float* __restrict__ Xm, float* __restrict__ ws) {
  int w = threadIdx.x >> 6, lane = threadIdx.x & 63;
  int row = blockIdx.x * 4 + w;
  const float4* p = (const float4*)(Xm + (size_t)row * DD) + lane * 2;
  float4 v0 = p[0], v1 = p[1];
  unsigned h[4], l[4];
  cvt2(v0.x, v0.y, h[0], l[0]); cvt2(v0.z, v0.w, h[1], l[1]);
  cvt2(v1.x, v1.y, h[2], l[2]); cvt2(v1.z, v1.w, h[3], l[3]);
  ((uint4*)(ws + WS_XH))[row * 64 + lane] = make_uint4(h[0], h[1], h[2], h[3]);
  ((uint4*)(ws + WS_XL))[row * 64 + lane] = make_uint4(l[0], l[1], l[2], l[3]);
}

/* ------- K1: fused data preconvert (tiled split-bf16) + row norms ------- */
__global__ __launch_bounds__(256) void convd_kernel(
    const float* __restrict__ dat, float* __restrict__ ws) {
  const int slice = blockIdx.x;            /* 0..390 */
  const int t = threadIdx.x;
  const int row = t >> 1, h2 = t & 1;      /* thread: 1 row x 256 k */
  const int gr = slice * NT + row;
  const int r15 = row & 15;
  float s = 0.f;
#pragma unroll
  for (int kc8 = 0; kc8 < 8; kc8++) {
    const int kc = h2 * 8 + kc8;
    float4 v[8];
    if (gr < NN) {
      const float4* src = (const float4*)(dat + (size_t)gr * DD + kc * 32);
#pragma unroll
      for (int j = 0; j < 8; j++) v[j] = src[j];
    } else {
#pragma unroll
      for (int j = 0; j < 8; j++) v[j] = make_float4(0.f, 0.f, 0.f, 0.f);
    }
    unsigned hw[16], lw[16];
#pragma unroll
    for (int j = 0; j < 8; j++) {
      s = fmaf(v[j].x, v[j].x, s); s = fmaf(v[j].y, v[j].y, s);
      s = fmaf(v[j].z, v[j].z, s); s = fmaf(v[j].w, v[j].w, s);
      cvt2(v[j].x, v[j].y, hw[2 * j], lw[2 * j]);
      cvt2(v[j].z, v[j].w, hw[2 * j + 1], lw[2 * j + 1]);
    }
    uint4* dhp = (uint4*)((unsigned char*)(ws + WS_DH) +
                          (((size_t)slice * 16 + kc) * 8 + (row >> 4)) * 1024);
    uint4* dlp = (uint4*)((unsigned char*)(ws + WS_DL) +
                          (((size_t)slice * 16 + kc) * 8 + (row >> 4)) * 1024);
#pragma unroll
    for (int qd = 0; qd < 4; qd++) {
      dhp[qd * 16 + r15] = make_uint4(hw[4 * qd], hw[4 * qd + 1], hw[4 * qd + 2], hw[4 * qd + 3]);
      dlp[qd * 16 + r15] = make_uint4(lw[4 * qd], lw[4 * qd + 1], lw[4 * qd + 2], lw[4 * qd + 3]);
    }
  }
  s += __shfl_xor(s, 1, 64);
  if (h2 == 0) ws[WS_D2 + gr] = (gr < NN) ? s : __builtin_inff();
}

/* ------- K2: GEMM core template (NT=128, 256 thr); MODE 0 = sampled
   full top-10, MODE 1 = filter (fallback only); PRE = tiled B ----------- */
struct StageT { unsigned char ah[8192], al[8192], bh[8192], bl[8192]; };
struct EpiT  { float sq[64][132]; };
struct ListT { u64 kl[64][4][KNN]; };
union SmemU { StageT s; EpiT e; ListT l; u64 tau[128]; };

template <int PRE, int MODE>
__global__ __launch_bounds__(256, 3) void knn_chunk(
    const float* __restrict__ dat, float* __restrict__ ws, int soff) {
  __shared__ __align__(16) SmemU sm;
  const int qbase = blockIdx.x * QTB;
  const int slice = blockIdx.y + soff;
  const int nbase = slice * NT;
  const int t = threadIdx.x;
  const int lane = t & 63, wave = t >> 6;
  const int wn = wave & 1, wq = wave >> 1;
  const unsigned short* xh = (const unsigned short*)(ws + WS_XH);
  const unsigned short* xl = (const unsigned short*)(ws + WS_XL);
  const unsigned char* dh = (const unsigned char*)(ws + WS_DH);
  const unsigned char* dl = (const unsigned char*)(ws + WS_DL);

  f32x4 acc[4][4];
#pragma unroll
  for (int i = 0; i < 4; i++)
#pragma unroll
    for (int j = 0; j < 4; j++) acc[i][j] = (f32x4)0.f;

  const int brow = t >> 1, bh_half = t & 1;
  const int bgr = nbase + brow;
  const int bpanel = (brow >> 4) * 1024;
  const int bchunk = (brow & 15) * 16;

  for (int kk = 0; kk < DD; kk += BK) {
    __syncthreads();
#pragma unroll
    for (int i = 0; i < 4; i++) {
      int pp = wave * 4 + i;
      int p = pp & 7;
      const unsigned short* g =
          (pp < 8 ? xh : xl) +
          (size_t)(qbase + p * 16 + (lane & 15)) * DD + kk + (lane >> 4) * 8;
      unsigned char* ldst = (pp < 8 ? sm.s.ah : sm.s.al) + p * 1024;
      glds16(g, ldst);
    }
    if (PRE) {
      const int kc = kk >> 5;
#pragma unroll
      for (int i = 0; i < 4; i++) {
        int pp = wave * 4 + i;
        int p = pp & 7;
        const unsigned char* g = (pp < 8 ? dh : dl) +
            (((size_t)slice * 16 + kc) * 8 + p) * 1024 + lane * 16;
        unsigned char* ldst = (pp < 8 ? sm.s.bh : sm.s.bl) + p * 1024;
        glds16(g, ldst);
      }
    } else {
      float4 v0 = make_float4(0.f, 0.f, 0.f, 0.f), v1 = v0, v2 = v0, v3 = v0;
      if (bgr < NN) {
        const float4* src = (const float4*)(dat + (size_t)bgr * DD + kk + bh_half * 16);
        v0 = src[0]; v1 = src[1]; v2 = src[2]; v3 = src[3];
      }
      unsigned hw[8], lw[8];
      cvt2(v0.x, v0.y, hw[0], lw[0]); cvt2(v0.z, v0.w, hw[1], lw[1]);
      cvt2(v1.x, v1.y, hw[2], lw[2]); cvt2(v1.z, v1.w, hw[3], lw[3]);
      cvt2(v2.x, v2.y, hw[4], lw[4]); cvt2(v2.z, v2.w, hw[5], lw[5]);
      cvt2(v3.x, v3.y, hw[6], lw[6]); cvt2(v3.z, v3.w, hw[7], lw[7]);
      unsigned char* bhp = sm.s.bh + bpanel;
      unsigned char* blp = sm.s.bl + bpanel;
      *(uint4*)(bhp + (2 * bh_half) * 256 + bchunk)     = make_uint4(hw[0], hw[1], hw[2], hw[3]);
      *(uint4*)(bhp + (2 * bh_half + 1) * 256 + bchunk) = make_uint4(hw[4], hw[5], hw[6], hw[7]);
      *(uint4*)(blp + (2 * bh_half) * 256 + bchunk)     = make_uint4(lw[0], lw[1], lw[2], lw[3]);
      *(uint4*)(blp + (2 * bh_half + 1) * 256 + bchunk) = make_uint4(lw[4], lw[5], lw[6], lw[7]);
    }
    __syncthreads();

    const int fragoff = lane * 16;
    short8 fah[4], fal[4], fbh[4], fbl[4];
#pragma unroll
    for (int i = 0; i < 4; i++) {
      fah[i] = *(const short8*)(sm.s.ah + (wq * 4 + i) * 1024 + fragoff);
      fal[i] = *(const short8*)(sm.s.al + (wq * 4 + i) * 1024 + fragoff);
      fbh[i] = *(const short8*)(sm.s.bh + (wn * 4 + i) * 1024 + fragoff);
      fbl[i] = *(const short8*)(sm.s.bl + (wn * 4 + i) * 1024 + fragoff);
    }
#pragma unroll
    for (int mt = 0; mt < 4; mt++)
#pragma unroll
      for (int nt = 0; nt < 4; nt++) {
        acc[mt][nt] = __builtin_amdgcn_mfma_f32_16x16x32_bf16(fah[mt], fbh[nt], acc[mt][nt], 0, 0, 0);
        acc[mt][nt] = __builtin_amdgcn_mfma_f32_16x16x32_bf16(fah[mt], fbl[nt], acc[mt][nt], 0, 0, 0);
        acc[mt][nt] = __builtin_amdgcn_mfma_f32_16x16x32_bf16(fal[mt], fbh[nt], acc[mt][nt], 0, 0, 0);
      }
  }

  if (MODE == 0) {
#pragma unroll
    for (int pass = 0; pass < 2; pass++) {
      __syncthreads();
      if (wq == pass) {
#pragma unroll
        for (int nt = 0; nt < 4; nt++) {
          int col = wn * 64 + nt * 16 + (lane & 15);
          float d2v = ws[WS_D2 + nbase + col];
#pragma unroll
          for (int mt = 0; mt < 4; mt++)
#pragma unroll
            for (int rg = 0; rg < 4; rg++) {
              int lr = mt * 16 + (lane >> 4) * 4 + rg;
              sm.e.sq[lr][col] = fmaf(-2.f, acc[mt][nt][rg], d2v);
            }
        }
      }
      __syncthreads();
      {
        const int r = t >> 2, s = t & 3;
        u64 kl[KNN];
#pragma unroll
        for (int u = 0; u < KNN; u++) kl[u] = ~0ull;
        for (int jj = 0; jj < 32; jj++) {
          int c = s * 32 + ((jj + r + 8 * s) & 31);
          float v = sm.e.sq[r][c];
          ins10(kl, mkkey(v, nbase + c));
        }
        __syncthreads();
#pragma unroll
        for (int u = 0; u < KNN; u++) sm.l.kl[r][s][u] = kl[u];
      }
      __syncthreads();
      if (t < 64) {
        u64* dst = ((u64*)(ws + WS_CKS)) +
                   ((size_t)(qbase + pass * 64 + t) * NSAMP + blockIdx.y) * KNN;
        int h0 = 0, h1 = 0, h2 = 0, h3 = 0;
        for (int pick = 0; pick < KNN; pick++) {
          u64 k0 = sm.l.kl[t][0][h0], k1 = sm.l.kl[t][1][h1];
          u64 k2 = sm.l.kl[t][2][h2], k3 = sm.l.kl[t][3][h3];
          u64 best = k0; int bm = 0;
          if (k1 < best) { best = k1; bm = 1; }
          if (k2 < best) { best = k2; bm = 2; }
          if (k3 < best) { best = k3; bm = 3; }
          dst[pick] = best;
          h0 += (bm == 0); h1 += (bm == 1); h2 += (bm == 2); h3 += (bm == 3);
        }
      }
    }
  } else {
    __syncthreads();
    if (t < 128) sm.tau[t] = ((const u64*)(ws + WS_TAU))[qbase + t];
    __syncthreads();
    unsigned* cnt = (unsigned*)(ws + WS_CNT);
    u64* buf = (u64*)(ws + WS_BUF);
    float d2v[4];
#pragma unroll
    for (int nt = 0; nt < 4; nt++)
      d2v[nt] = ws[WS_D2 + nbase + wn * 64 + nt * 16 + (lane & 15)];
#pragma unroll
    for (int mt = 0; mt < 4; mt++)
#pragma unroll
      for (int rg = 0; rg < 4; rg++) {
        int row = wq * 64 + mt * 16 + (lane >> 4) * 4 + rg;
        u64 tr = sm.tau[row];
#pragma unroll
        for (int nt = 0; nt < 4; nt++) {
          float d = fmaf(-2.f, acc[mt][nt][rg], d2v[nt]);
          int col = nbase + wn * 64 + nt * 16 + (lane & 15);
          u64 key = mkkey(d, col);
          if (key < tr) {
            int q = qbase + row;
            unsigned slot = atomicAdd(cnt + q, 1u);
            if (slot < CAP) buf[(size_t)q * CAP + slot] = key;
          }
        }
      }
  }
}

/* ------- K2f: 512-thr filter, 128q x 256n per block (slice pair) -------
   8 waves of 64x64; per-wave regs identical to knn_chunk; LDS 49 KB.    */
struct StageF { unsigned char ah[8192], al[8192], bh[16384], bl[16384]; };

__global__ __launch_bounds__(512, 4) void knn_filter(float* __restrict__ ws) {
  __shared__ __align__(16) StageF sm;
  __shared__ u64 stau[128];
  const int qbase = blockIdx.x * QTB;
  const int slice0 = NSAMP + blockIdx.y * 2;
  const int nbase = slice0 * NT;           /* covers 256 cols */
  const int t = threadIdx.x;
  const int lane = t & 63, wave = t >> 6;  /* 0..7 */
  const int wn = wave & 3, wq = wave >> 2;
  const unsigned short* xh = (const unsigned short*)(ws + WS_XH);
  const unsigned short* xl = (const unsigned short*)(ws + WS_XL);
  const unsigned char* dh = (const unsigned char*)(ws + WS_DH);
  const unsigned char* dl = (const unsigned char*)(ws + WS_DL);

  if (t < 128) stau[t] = ((const u64*)(ws + WS_TAU))[qbase + t];

  f32x4 acc[4][4];
#pragma unroll
  for (int i = 0; i < 4; i++)
#pragma unroll
    for (int j = 0; j < 4; j++) acc[i][j] = (f32x4)0.f;

  for (int kk = 0; kk < DD; kk += BK) {
    __syncthreads();
    /* A: 16 panels / 8 waves = 2 each */
#pragma unroll
    for (int i = 0; i < 2; i++) {
      int pp = wave * 2 + i;
      int p = pp & 7;
      const unsigned short* g = (pp < 8 ? xh : xl) +
          (size_t)(qbase + p * 16 + (lane & 15)) * DD + kk + (lane >> 4) * 8;
      unsigned char* ldst = (pp < 8 ? sm.ah : sm.al) + p * 1024;
      glds16(g, ldst);
    }
    /* B: 32 panels (2 slices x hi/lo) / 8 waves = 4 each */
    const int kc = kk >> 5;
#pragma unroll
    for (int i = 0; i < 4; i++) {
      int pp = wave * 4 + i;
      int p = pp & 15;
      const unsigned char* g = (pp < 16 ? dh : dl) +
          (((size_t)(slice0 + (p >> 3)) * 16 + kc) * 8 + (p & 7)) * 1024 + lane * 16;
      unsigned char* ldst = (pp < 16 ? sm.bh : sm.bl) + p * 1024;
      glds16(g, ldst);
    }
    __syncthreads();

    const int fragoff = lane * 16;
    short8 fah[4], fal[4], fbh[4], fbl[4];
#pragma unroll
    for (int i = 0; i < 4; i++) {
      fah[i] = *(const short8*)(sm.ah + (wq * 4 + i) * 1024 + fragoff);
      fal[i] = *(const short8*)(sm.al + (wq * 4 + i) * 1024 + fragoff);
      fbh[i] = *(const short8*)(sm.bh + (wn * 4 + i) * 1024 + fragoff);
      fbl[i] = *(const short8*)(sm.bl + (wn * 4 + i) * 1024 + fragoff);
    }
#pragma unroll
    for (int mt = 0; mt < 4; mt++)
#pragma unroll
      for (int nt = 0; nt < 4; nt++) {
        acc[mt][nt] = __builtin_amdgcn_mfma_f32_16x16x32_bf16(fah[mt], fbh[nt], acc[mt][nt], 0, 0, 0);
        acc[mt][nt] = __builtin_amdgcn_mfma_f32_16x16x32_bf16(fah[mt], fbl[nt], acc[mt][nt], 0, 0, 0);
        acc[mt][nt] = __builtin_amdgcn_mfma_f32_16x16x32_bf16(fal[mt], fbh[nt], acc[mt][nt], 0, 0, 0);
      }
  }

  unsigned* cnt = (unsigned*)(ws + WS_CNT);
  u64* buf = (u64*)(ws + WS_BUF);
  float d2v[4];
#pragma unroll
  for (int nt = 0; nt < 4; nt++)
    d2v[nt] = ws[WS_D2 + nbase + wn * 64 + nt * 16 + (lane & 15)];
#pragma unroll
  for (int mt = 0; mt < 4; mt++)
#pragma unroll
    for (int rg = 0; rg < 4; rg++) {
      int row = wq * 64 + mt * 16 + (lane >> 4) * 4 + rg;
      u64 tr = stau[row];
#pragma unroll
      for (int nt = 0; nt < 4; nt++) {
        float d = fmaf(-2.f, acc[mt][nt][rg], d2v[nt]);
        int col = nbase + wn * 64 + nt * 16 + (lane & 15);
        u64 key = mkkey(d, col);
        if (key < tr) {
          int q = qbase + row;
          unsigned slot = atomicAdd(cnt + q, 1u);
          if (slot < CAP) buf[(size_t)q * CAP + slot] = key;
        }
      }
    }
}

/* ---------------- K2t: per-query tau = 10th of sampled keys ------------ */
__global__ __launch_bounds__(64) void tau_kernel(float* __restrict__ ws) {
  const int q = blockIdx.x;
  const int t = threadIdx.x;
  const u64* samp = ((const u64*)(ws + WS_CKS)) + (size_t)q * NSAMP * KNN;
  const int NC = NSAMP * KNN;
  u64 kl[KNN];
#pragma unroll
  for (int u = 0; u < KNN; u++) kl[u] = ~0ull;
  for (int j = t; j < NC; j += 64) ins10(kl, samp[j]);
  __shared__ u64 wk[64][KNN];
  __shared__ u64 m2[8][KNN];
#pragma unroll
  for (int u = 0; u < KNN; u++) wk[t][u] = kl[u];
  __syncthreads();
  if (t < 8) {
    int h[8] = {0, 0, 0, 0, 0, 0, 0, 0};
    for (int pick = 0; pick < KNN; pick++) {
      u64 best = ~0ull; int bm = 0;
#pragma unroll
      for (int m = 0; m < 8; m++) {
        u64 km = wk[t * 8 + m][h[m]];
        if (km < best) { best = km; bm = m; }
      }
      m2[t][pick] = best;
#pragma unroll
      for (int m = 0; m < 8; m++) h[m] += (bm == m);
    }
  }
  __syncthreads();
  if (t == 0) {
    int h[8] = {0, 0, 0, 0, 0, 0, 0, 0};
    u64 best = 0;
    for (int pick = 0; pick < KNN; pick++) {
      best = ~0ull; int bm = 0;
#pragma unroll
      for (int m = 0; m < 8; m++) {
        u64 km = m2[m][h[m]];
        if (km < best) { best = km; bm = m; }
      }
#pragma unroll
      for (int m = 0; m < 8; m++) h[m] += (bm == m);
    }
    ((u64*)(ws + WS_TAU))[q] = best;
    ((unsigned*)(ws + WS_CNT))[q] = 0u;
  }
}

/* ---------------- K3: final top-10 (sampled + survivors) + mode -------- */
__global__ __launch_bounds__(64) void knn_final(
    const int* __restrict__ targets, float* __restrict__ ws,
    float* __restrict__ out) {
  const int q = blockIdx.x;
  const int t = threadIdx.x;
  const u64* samp = ((const u64*)(ws + WS_CKS)) + (size_t)q * NSAMP * KNN;
  const u64* buf = ((const u64*)(ws + WS_BUF)) + (size_t)q * CAP;
  unsigned c = ((const unsigned*)(ws + WS_CNT))[q];
  if (c > CAP) c = CAP;

  u64 kl[KNN];
#pragma unroll
  for (int u = 0; u < KNN; u++) kl[u] = ~0ull;
  for (int j = t; j < NSAMP * KNN; j += 64) ins10(kl, samp[j]);
  for (int j = t; j < (int)c; j += 64) ins10(kl, buf[j]);

  __shared__ u64 wk[64][KNN];
  __shared__ u64 m2[8][KNN];
#pragma unroll
  for (int u = 0; u < KNN; u++) wk[t][u] = kl[u];
  __syncthreads();
  if (t < 8) {
    int h[8] = {0, 0, 0, 0, 0, 0, 0, 0};
    for (int pick = 0; pick < KNN; pick++) {
      u64 best = ~0ull; int bm = 0;
#pragma unroll
      for (int m = 0; m < 8; m++) {
        u64 km = wk[t * 8 + m][h[m]];
        if (km < best) { best = km; bm = m; }
      }
      m2[t][pick] = best;
#pragma unroll
      for (int m = 0; m < 8; m++) h[m] += (bm == m);
    }
  }
  __syncthreads();
  if (t == 0) {
    int h[8] = {0, 0, 0, 0, 0, 0, 0, 0};
    int fi[KNN];
    for (int pick = 0; pick < KNN; pick++) {
      u64 best = ~0ull; int bm = 0;
#pragma unroll
      for (int m = 0; m < 8; m++) {
        u64 km = m2[m][h[m]];
        if (km < best) { best = km; bm = m; }
      }
      fi[pick] = (int)(unsigned)(best & 0xffffffffu);
#pragma unroll
      for (int m = 0; m < 8; m++) h[m] += (bm == m);
    }
    int lab[KNN];
#pragma unroll
    for (int u = 0; u < KNN; u++) lab[u] = targets[fi[u]];
    int bc = 0, bl = INT_MAX;
#pragma unroll
    for (int i = 0; i < KNN; i++) {
      int cc = 0;
#pragma unroll
      for (int j = 0; j < KNN; j++) cc += (lab[j] == lab[i]) ? 1 : 0;
      if (cc > bc || (cc == bc && lab[i] < bl)) { bc = cc; bl = lab[i]; }
    }
    out[q] = (float)bl;
  }
}

extern "C" void kernel_launch(void* const* d_in, const int* in_sizes, int n_in,
                              void* d_out, int out_size, void* d_ws, size_t ws_size,
                              hipStream_t stream) {
  const float* Xm  = (const float*)d_in[0];
  const float* dat = (const float*)d_in[1];
  const int* targets = (const int*)d_in[2];
  float* out = (float*)d_out;
  float* ws  = (float*)d_ws;
  const bool pre = ws_size >= (size_t)WS_END * 4;   /* constant per process */

  hipLaunchKernelGGL(convx_kernel, dim3(QN / 4), dim3(256), 0, stream, Xm, ws);
  if (pre) {
    hipLaunchKernelGGL(convd_kernel, dim3(NS), dim3(256), 0, stream, dat, ws);
    hipLaunchKernelGGL((knn_chunk<1, 0>), dim3(QB, NSAMP), dim3(256), 0, stream, dat, ws, 0);
    hipLaunchKernelGGL(tau_kernel, dim3(QN), dim3(64), 0, stream, ws);
    hipLaunchKernelGGL(knn_filter, dim3(QB, NPAIR), dim3(512), 0, stream, ws);
  } else {
    /* fallback: no tiled-B image; still needs norms -> use convd's norms via
       a data pass with writes to WS_DH skipped is not available; compute
       norms with the sampled/filter kernels' d2 source: do a norms pass. */
    hipLaunchKernelGGL(convd_kernel, dim3(NS), dim3(256), 0, stream, dat, ws);
    hipLaunchKernelGGL((knn_chunk<0, 0>), dim3(QB, NSAMP), dim3(256), 0, stream, dat, ws, 0);
    hipLaunchKernelGGL(tau_kernel, dim3(QN), dim3(64), 0, stream, ws);
    hipLaunchKernelGGL((knn_chunk<0, 1>), dim3(QB, NREST), dim3(256), 0, stream, dat, ws, NSAMP);
  }
  hipLaunchKernelGGL(knn_final, dim3(QN), dim3(64), 0, stream, targets, ws, out);
}

// Round 8
// 390.924 us; speedup vs baseline: 1.0625x; 1.0625x over previous
//
#include <hip/hip_runtime.h>
#include <math.h>
#include <limits.h>

#define QN 1024
#define NN 50000
#define NPAD 50048        /* 391*128 exactly */
#define DD 512
#define KNN 10
#define NT 128
#define QTB 128
#define BK 32
#define NS 391
#define QB 8
#define NSAMP 31
#define NREST (NS - NSAMP)    /* 360 */
#define CAP 512

/* workspace layout, in 4-byte words */
#define WS_D2  0
#define WS_TAU 50048                       /* u64[1024] */
#define WS_CNT (WS_TAU + 2048)
#define WS_XH  (WS_CNT + 1024)
#define WS_XL  (WS_XH + QN * DD / 2)
#define WS_CKS (WS_XL + QN * DD / 2)       /* u64[QN*NSAMP*KNN] */
#define WS_BUF (WS_CKS + QN * NSAMP * KNN * 2)
#define WS_DH  (WS_BUF + QN * CAP * 2)     /* tiled data hi: 391*16*8192 B */
#define WS_DL  (WS_DH + NS * 16 * 2048)
#define WS_END (WS_DL + NS * 16 * 2048)

typedef __attribute__((ext_vector_type(8))) short short8;
typedef __attribute__((ext_vector_type(4))) float f32x4;
typedef unsigned long long u64;

__device__ __forceinline__ u64 mkkey(float f, int idx) {
  unsigned u = __float_as_uint(f);
  unsigned m = u ^ ((unsigned)((int)u >> 31) | 0x80000000u);
  return ((u64)m << 32) | (unsigned)idx;
}

__device__ __forceinline__ void cvt2(float x, float y, unsigned& hi, unsigned& lo) {
  unsigned ux = __float_as_uint(x), uy = __float_as_uint(y);
  unsigned rx = ux + 0x7fffu + ((ux >> 16) & 1u);
  unsigned ry = uy + 0x7fffu + ((uy >> 16) & 1u);
  hi = (rx >> 16) | (ry & 0xffff0000u);
  float xl = x - __uint_as_float(rx & 0xffff0000u);
  float yl = y - __uint_as_float(ry & 0xffff0000u);
  unsigned uxl = __float_as_uint(xl), uyl = __float_as_uint(yl);
  unsigned rxl = uxl + 0x7fffu + ((uxl >> 16) & 1u);
  unsigned ryl = uyl + 0x7fffu + ((uyl >> 16) & 1u);
  lo = (rxl >> 16) | (ryl & 0xffff0000u);
}

__device__ __forceinline__ void glds16(const void* g, void* l) {
  __builtin_amdgcn_global_load_lds(
      (const __attribute__((address_space(1))) unsigned*)g,
      (__attribute__((address_space(3))) unsigned*)l, 16, 0, 0);
}

__device__ __forceinline__ void ins10(u64* kl, u64 k) {
#pragma unroll
  for (int u = 0; u < KNN; u++) {
    u64 lo = (k < kl[u]) ? k : kl[u];
    u64 hi = (k < kl[u]) ? kl[u] : k;
    kl[u] = lo; k = hi;
  }
}

/* ---------------- K0: preconvert X to split-bf16 row-major -------------- */
__global__ __launch_bounds__(256) void convx_kernel(
    const float* __restrict__ Xm, float* __restrict__ ws) {
  int w = threadIdx.x >> 6, lane = threadIdx.x & 63;
  int row = blockIdx.x * 4 + w;
  const float4* p = (const float4*)(Xm + (size_t)row * DD) + lane * 2;
  float4 v0 = p[0], v1 = p[1];
  unsigned h[4], l[4];
  cvt2(v0.x, v0.y, h[0], l[0]); cvt2(v0.z, v0.w, h[1], l[1]);
  cvt2(v1.x, v1.y, h[2], l[2]); cvt2(v1.z, v1.w, h[3], l[3]);
  ((uint4*)(ws + WS_XH))[row * 64 + lane] = make_uint4(h[0], h[1], h[2], h[3]);
  ((uint4*)(ws + WS_XL))[row * 64 + lane] = make_uint4(l[0], l[1], l[2], l[3]);
}

/* ------- K1: fused data preconvert (tiled split-bf16) + row norms ------- */
__global__ __launch_bounds__(256) void convd_kernel(
    const float* __restrict__ dat, float* __restrict__ ws) {
  const int slice = blockIdx.x;
  const int t = threadIdx.x;
  const int row = t >> 1, h2 = t & 1;
  const int gr = slice * NT + row;
  const int r15 = row & 15;
  float s = 0.f;
#pragma unroll
  for (int kc8 = 0; kc8 < 8; kc8++) {
    const int kc = h2 * 8 + kc8;
    float4 v[8];
    if (gr < NN) {
      const float4* src = (const float4*)(dat + (size_t)gr * DD + kc * 32);
#pragma unroll
      for (int j = 0; j < 8; j++) v[j] = src[j];
    } else {
#pragma unroll
      for (int j = 0; j < 8; j++) v[j] = make_float4(0.f, 0.f, 0.f, 0.f);
    }
    unsigned hw[16], lw[16];
#pragma unroll
    for (int j = 0; j < 8; j++) {
      s = fmaf(v[j].x, v[j].x, s); s = fmaf(v[j].y, v[j].y, s);
      s = fmaf(v[j].z, v[j].z, s); s = fmaf(v[j].w, v[j].w, s);
      cvt2(v[j].x, v[j].y, hw[2 * j], lw[2 * j]);
      cvt2(v[j].z, v[j].w, hw[2 * j + 1], lw[2 * j + 1]);
    }
    uint4* dhp = (uint4*)((unsigned char*)(ws + WS_DH) +
                          (((size_t)slice * 16 + kc) * 8 + (row >> 4)) * 1024);
    uint4* dlp = (uint4*)((unsigned char*)(ws + WS_DL) +
                          (((size_t)slice * 16 + kc) * 8 + (row >> 4)) * 1024);
#pragma unroll
    for (int qd = 0; qd < 4; qd++) {
      dhp[qd * 16 + r15] = make_uint4(hw[4 * qd], hw[4 * qd + 1], hw[4 * qd + 2], hw[4 * qd + 3]);
      dlp[qd * 16 + r15] = make_uint4(lw[4 * qd], lw[4 * qd + 1], lw[4 * qd + 2], lw[4 * qd + 3]);
    }
  }
  s += __shfl_xor(s, 1, 64);
  if (h2 == 0) ws[WS_D2 + gr] = (gr < NN) ? s : __builtin_inff();
}

/* ------- K2: GEMM core (NT=128, 256 thr); MODE 0 = sampled full top-10,
   MODE 1 = threshold filter; PRE 1 = register-prefetch pipelined K-loop -- */
struct StageT { unsigned char ah[8192], al[8192], bh[8192], bl[8192]; };
struct EpiT  { float sq[64][132]; };
struct ListT { u64 kl[64][4][KNN]; };
union SmemU { StageT s; EpiT e; ListT l; u64 tau[128]; };

template <int PRE, int MODE>
__global__ __launch_bounds__(256, 3) void knn_chunk(
    const float* __restrict__ dat, float* __restrict__ ws, int soff) {
  __shared__ __align__(16) SmemU sm;
  const int qbase = blockIdx.x * QTB;
  const int slice = blockIdx.y + soff;
  const int nbase = slice * NT;
  const int t = threadIdx.x;
  const int lane = t & 63, wave = t >> 6;
  const int wn = wave & 1, wq = wave >> 1;
  const unsigned short* xh = (const unsigned short*)(ws + WS_XH);
  const unsigned short* xl = (const unsigned short*)(ws + WS_XL);
  const unsigned char* dh = (const unsigned char*)(ws + WS_DH);
  const unsigned char* dl = (const unsigned char*)(ws + WS_DL);

  f32x4 acc[4][4];
#pragma unroll
  for (int i = 0; i < 4; i++)
#pragma unroll
    for (int j = 0; j < 4; j++) acc[i][j] = (f32x4)0.f;

  if (PRE) {
    /* pipelined: DMA(kc+1) issued after frag reads, overlaps MFMA(kc) */
    auto stage = [&](int kc) {
#pragma unroll
      for (int i = 0; i < 4; i++) {
        int pp = wave * 4 + i;
        int p = pp & 7;
        const unsigned short* g = (pp < 8 ? xh : xl) +
            (size_t)(qbase + p * 16 + (lane & 15)) * DD + kc * 32 + (lane >> 4) * 8;
        glds16(g, (pp < 8 ? sm.s.ah : sm.s.al) + p * 1024);
      }
#pragma unroll
      for (int i = 0; i < 4; i++) {
        int pp = wave * 4 + i;
        int p = pp & 7;
        const unsigned char* g = (pp < 8 ? dh : dl) +
            (((size_t)slice * 16 + kc) * 8 + p) * 1024 + lane * 16;
        glds16(g, (pp < 8 ? sm.s.bh : sm.s.bl) + p * 1024);
      }
    };
    stage(0);
    for (int kc = 0; kc < 16; kc++) {
      __syncthreads();                    /* DMA(kc) complete */
      const int fragoff = lane * 16;
      short8 fah[4], fal[4], fbh[4], fbl[4];
#pragma unroll
      for (int i = 0; i < 4; i++) {
        fah[i] = *(const short8*)(sm.s.ah + (wq * 4 + i) * 1024 + fragoff);
        fal[i] = *(const short8*)(sm.s.al + (wq * 4 + i) * 1024 + fragoff);
        fbh[i] = *(const short8*)(sm.s.bh + (wn * 4 + i) * 1024 + fragoff);
        fbl[i] = *(const short8*)(sm.s.bl + (wn * 4 + i) * 1024 + fragoff);
      }
      __syncthreads();                    /* all waves done reading LDS */
      if (kc < 15) stage(kc + 1);         /* overlaps the MFMAs below */
      /* 3 sweeps of 16: consecutive MFMAs never share an accumulator */
#pragma unroll
      for (int mt = 0; mt < 4; mt++)
#pragma unroll
        for (int nt = 0; nt < 4; nt++)
          acc[mt][nt] = __builtin_amdgcn_mfma_f32_16x16x32_bf16(fah[mt], fbh[nt], acc[mt][nt], 0, 0, 0);
#pragma unroll
      for (int mt = 0; mt < 4; mt++)
#pragma unroll
        for (int nt = 0; nt < 4; nt++)
          acc[mt][nt] = __builtin_amdgcn_mfma_f32_16x16x32_bf16(fah[mt], fbl[nt], acc[mt][nt], 0, 0, 0);
#pragma unroll
      for (int mt = 0; mt < 4; mt++)
#pragma unroll
        for (int nt = 0; nt < 4; nt++)
          acc[mt][nt] = __builtin_amdgcn_mfma_f32_16x16x32_bf16(fal[mt], fbh[nt], acc[mt][nt], 0, 0, 0);
    }
  } else {
    /* fallback: in-loop B conversion (no tiled image in workspace) */
    const int brow = t >> 1, bh_half = t & 1;
    const int bgr = nbase + brow;
    const int bpanel = (brow >> 4) * 1024;
    const int bchunk = (brow & 15) * 16;
    for (int kk = 0; kk < DD; kk += BK) {
      __syncthreads();
#pragma unroll
      for (int i = 0; i < 4; i++) {
        int pp = wave * 4 + i;
        int p = pp & 7;
        const unsigned short* g = (pp < 8 ? xh : xl) +
            (size_t)(qbase + p * 16 + (lane & 15)) * DD + kk + (lane >> 4) * 8;
        glds16(g, (pp < 8 ? sm.s.ah : sm.s.al) + p * 1024);
      }
      {
        float4 v0 = make_float4(0.f, 0.f, 0.f, 0.f), v1 = v0, v2 = v0, v3 = v0;
        if (bgr < NN) {
          const float4* src = (const float4*)(dat + (size_t)bgr * DD + kk + bh_half * 16);
          v0 = src[0]; v1 = src[1]; v2 = src[2]; v3 = src[3];
        }
        unsigned hw[8], lw[8];
        cvt2(v0.x, v0.y, hw[0], lw[0]); cvt2(v0.z, v0.w, hw[1], lw[1]);
        cvt2(v1.x, v1.y, hw[2], lw[2]); cvt2(v1.z, v1.w, hw[3], lw[3]);
        cvt2(v2.x, v2.y, hw[4], lw[4]); cvt2(v2.z, v2.w, hw[5], lw[5]);
        cvt2(v3.x, v3.y, hw[6], lw[6]); cvt2(v3.z, v3.w, hw[7], lw[7]);
        unsigned char* bhp = sm.s.bh + bpanel;
        unsigned char* blp = sm.s.bl + bpanel;
        *(uint4*)(bhp + (2 * bh_half) * 256 + bchunk)     = make_uint4(hw[0], hw[1], hw[2], hw[3]);
        *(uint4*)(bhp + (2 * bh_half + 1) * 256 + bchunk) = make_uint4(hw[4], hw[5], hw[6], hw[7]);
        *(uint4*)(blp + (2 * bh_half) * 256 + bchunk)     = make_uint4(lw[0], lw[1], lw[2], lw[3]);
        *(uint4*)(blp + (2 * bh_half + 1) * 256 + bchunk) = make_uint4(lw[4], lw[5], lw[6], lw[7]);
      }
      __syncthreads();
      const int fragoff = lane * 16;
      short8 fah[4], fal[4], fbh[4], fbl[4];
#pragma unroll
      for (int i = 0; i < 4; i++) {
        fah[i] = *(const short8*)(sm.s.ah + (wq * 4 + i) * 1024 + fragoff);
        fal[i] = *(const short8*)(sm.s.al + (wq * 4 + i) * 1024 + fragoff);
        fbh[i] = *(const short8*)(sm.s.bh + (wn * 4 + i) * 1024 + fragoff);
        fbl[i] = *(const short8*)(sm.s.bl + (wn * 4 + i) * 1024 + fragoff);
      }
#pragma unroll
      for (int mt = 0; mt < 4; mt++)
#pragma unroll
        for (int nt = 0; nt < 4; nt++) {
          acc[mt][nt] = __builtin_amdgcn_mfma_f32_16x16x32_bf16(fah[mt], fbh[nt], acc[mt][nt], 0, 0, 0);
          acc[mt][nt] = __builtin_amdgcn_mfma_f32_16x16x32_bf16(fah[mt], fbl[nt], acc[mt][nt], 0, 0, 0);
          acc[mt][nt] = __builtin_amdgcn_mfma_f32_16x16x32_bf16(fal[mt], fbh[nt], acc[mt][nt], 0, 0, 0);
        }
    }
  }

  if (MODE == 0) {
#pragma unroll
    for (int pass = 0; pass < 2; pass++) {
      __syncthreads();
      if (wq == pass) {
#pragma unroll
        for (int nt = 0; nt < 4; nt++) {
          int col = wn * 64 + nt * 16 + (lane & 15);
          float d2v = ws[WS_D2 + nbase + col];
#pragma unroll
          for (int mt = 0; mt < 4; mt++)
#pragma unroll
            for (int rg = 0; rg < 4; rg++) {
              int lr = mt * 16 + (lane >> 4) * 4 + rg;
              sm.e.sq[lr][col] = fmaf(-2.f, acc[mt][nt][rg], d2v);
            }
        }
      }
      __syncthreads();
      {
        const int r = t >> 2, s = t & 3;
        u64 kl[KNN];
#pragma unroll
        for (int u = 0; u < KNN; u++) kl[u] = ~0ull;
        for (int jj = 0; jj < 32; jj++) {
          int c = s * 32 + ((jj + r + 8 * s) & 31);
          float v = sm.e.sq[r][c];
          ins10(kl, mkkey(v, nbase + c));
        }
        __syncthreads();
#pragma unroll
        for (int u = 0; u < KNN; u++) sm.l.kl[r][s][u] = kl[u];
      }
      __syncthreads();
      if (t < 64) {
        u64* dst = ((u64*)(ws + WS_CKS)) +
                   ((size_t)(qbase + pass * 64 + t) * NSAMP + blockIdx.y) * KNN;
        int h0 = 0, h1 = 0, h2 = 0, h3 = 0;
        for (int pick = 0; pick < KNN; pick++) {
          u64 k0 = sm.l.kl[t][0][h0], k1 = sm.l.kl[t][1][h1];
          u64 k2 = sm.l.kl[t][2][h2], k3 = sm.l.kl[t][3][h3];
          u64 best = k0; int bm = 0;
          if (k1 < best) { best = k1; bm = 1; }
          if (k2 < best) { best = k2; bm = 2; }
          if (k3 < best) { best = k3; bm = 3; }
          dst[pick] = best;
          h0 += (bm == 0); h1 += (bm == 1); h2 += (bm == 2); h3 += (bm == 3);
        }
      }
    }
  } else {
    __syncthreads();
    if (t < 128) sm.tau[t] = ((const u64*)(ws + WS_TAU))[qbase + t];
    __syncthreads();
    unsigned* cnt = (unsigned*)(ws + WS_CNT);
    u64* buf = (u64*)(ws + WS_BUF);
    float d2v[4];
#pragma unroll
    for (int nt = 0; nt < 4; nt++)
      d2v[nt] = ws[WS_D2 + nbase + wn * 64 + nt * 16 + (lane & 15)];
#pragma unroll
    for (int mt = 0; mt < 4; mt++)
#pragma unroll
      for (int rg = 0; rg < 4; rg++) {
        int row = wq * 64 + mt * 16 + (lane >> 4) * 4 + rg;
        u64 tr = sm.tau[row];
#pragma unroll
        for (int nt = 0; nt < 4; nt++) {
          float d = fmaf(-2.f, acc[mt][nt][rg], d2v[nt]);
          int col = nbase + wn * 64 + nt * 16 + (lane & 15);
          u64 key = mkkey(d, col);
          if (key < tr) {
            int q = qbase + row;
            unsigned slot = atomicAdd(cnt + q, 1u);
            if (slot < CAP) buf[(size_t)q * CAP + slot] = key;
          }
        }
      }
  }
}

/* ---------------- K2t: per-query tau = 10th of sampled keys ------------ */
__global__ __launch_bounds__(64) void tau_kernel(float* __restrict__ ws) {
  const int q = blockIdx.x;
  const int t = threadIdx.x;
  const u64* samp = ((const u64*)(ws + WS_CKS)) + (size_t)q * NSAMP * KNN;
  const int NC = NSAMP * KNN;
  u64 kl[KNN];
#pragma unroll
  for (int u = 0; u < KNN; u++) kl[u] = ~0ull;
  for (int j = t; j < NC; j += 64) ins10(kl, samp[j]);
  __shared__ u64 wk[64][KNN];
  __shared__ u64 m2[8][KNN];
#pragma unroll
  for (int u = 0; u < KNN; u++) wk[t][u] = kl[u];
  __syncthreads();
  if (t < 8) {
    int h[8] = {0, 0, 0, 0, 0, 0, 0, 0};
    for (int pick = 0; pick < KNN; pick++) {
      u64 best = ~0ull; int bm = 0;
#pragma unroll
      for (int m = 0; m < 8; m++) {
        u64 km = wk[t * 8 + m][h[m]];
        if (km < best) { best = km; bm = m; }
      }
      m2[t][pick] = best;
#pragma unroll
      for (int m = 0; m < 8; m++) h[m] += (bm == m);
    }
  }
  __syncthreads();
  if (t == 0) {
    int h[8] = {0, 0, 0, 0, 0, 0, 0, 0};
    u64 best = 0;
    for (int pick = 0; pick < KNN; pick++) {
      best = ~0ull; int bm = 0;
#pragma unroll
      for (int m = 0; m < 8; m++) {
        u64 km = m2[m][h[m]];
        if (km < best) { best = km; bm = m; }
      }
#pragma unroll
      for (int m = 0; m < 8; m++) h[m] += (bm == m);
    }
    ((u64*)(ws + WS_TAU))[q] = best;
    ((unsigned*)(ws + WS_CNT))[q] = 0u;
  }
}

/* ---------------- K3: final top-10 (sampled + survivors) + mode -------- */
__global__ __launch_bounds__(64) void knn_final(
    const int* __restrict__ targets, float* __restrict__ ws,
    float* __restrict__ out) {
  const int q = blockIdx.x;
  const int t = threadIdx.x;
  const u64* samp = ((const u64*)(ws + WS_CKS)) + (size_t)q * NSAMP * KNN;
  const u64* buf = ((const u64*)(ws + WS_BUF)) + (size_t)q * CAP;
  unsigned c = ((const unsigned*)(ws + WS_CNT))[q];
  if (c > CAP) c = CAP;

  u64 kl[KNN];
#pragma unroll
  for (int u = 0; u < KNN; u++) kl[u] = ~0ull;
  for (int j = t; j < NSAMP * KNN; j += 64) ins10(kl, samp[j]);
  for (int j = t; j < (int)c; j += 64) ins10(kl, buf[j]);

  __shared__ u64 wk[64][KNN];
  __shared__ u64 m2[8][KNN];
#pragma unroll
  for (int u = 0; u < KNN; u++) wk[t][u] = kl[u];
  __syncthreads();
  if (t < 8) {
    int h[8] = {0, 0, 0, 0, 0, 0, 0, 0};
    for (int pick = 0; pick < KNN; pick++) {
      u64 best = ~0ull; int bm = 0;
#pragma unroll
      for (int m = 0; m < 8; m++) {
        u64 km = wk[t * 8 + m][h[m]];
        if (km < best) { best = km; bm = m; }
      }
      m2[t][pick] = best;
#pragma unroll
      for (int m = 0; m < 8; m++) h[m] += (bm == m);
    }
  }
  __syncthreads();
  if (t == 0) {
    int h[8] = {0, 0, 0, 0, 0, 0, 0, 0};
    int fi[KNN];
    for (int pick = 0; pick < KNN; pick++) {
      u64 best = ~0ull; int bm = 0;
#pragma unroll
      for (int m = 0; m < 8; m++) {
        u64 km = m2[m][h[m]];
        if (km < best) { best = km; bm = m; }
      }
      fi[pick] = (int)(unsigned)(best & 0xffffffffu);
#pragma unroll
      for (int m = 0; m < 8; m++) h[m] += (bm == m);
    }
    int lab[KNN];
#pragma unroll
    for (int u = 0; u < KNN; u++) lab[u] = targets[fi[u]];
    int bc = 0, bl = INT_MAX;
#pragma unroll
    for (int i = 0; i < KNN; i++) {
      int cc = 0;
#pragma unroll
      for (int j = 0; j < KNN; j++) cc += (lab[j] == lab[i]) ? 1 : 0;
      if (cc > bc || (cc == bc && lab[i] < bl)) { bc = cc; bl = lab[i]; }
    }
    out[q] = (float)bl;
  }
}

extern "C" void kernel_launch(void* const* d_in, const int* in_sizes, int n_in,
                              void* d_out, int out_size, void* d_ws, size_t ws_size,
                              hipStream_t stream) {
  const float* Xm  = (const float*)d_in[0];
  const float* dat = (const float*)d_in[1];
  const int* targets = (const int*)d_in[2];
  float* out = (float*)d_out;
  float* ws  = (float*)d_ws;
  const bool pre = ws_size >= (size_t)WS_END * 4;   /* constant per process */

  hipLaunchKernelGGL(convx_kernel, dim3(QN / 4), dim3(256), 0, stream, Xm, ws);
  hipLaunchKernelGGL(convd_kernel, dim3(NS), dim3(256), 0, stream, dat, ws);
  if (pre) {
    hipLaunchKernelGGL((knn_chunk<1, 0>), dim3(QB, NSAMP), dim3(256), 0, stream, dat, ws, 0);
    hipLaunchKernelGGL(tau_kernel, dim3(QN), dim3(64), 0, stream, ws);
    hipLaunchKernelGGL((knn_chunk<1, 1>), dim3(QB, NREST), dim3(256), 0, stream, dat, ws, NSAMP);
  } else {
    hipLaunchKernelGGL((knn_chunk<0, 0>), dim3(QB, NSAMP), dim3(256), 0, stream, dat, ws, 0);
    hipLaunchKernelGGL(tau_kernel, dim3(QN), dim3(64), 0, stream, ws);
    hipLaunchKernelGGL((knn_chunk<0, 1>), dim3(QB, NREST), dim3(256), 0, stream, dat, ws, NSAMP);
  }
  hipLaunchKernelGGL(knn_final, dim3(QN), dim3(64), 0, stream, targets, ws, out);
}